// Round 1
// baseline (164.282 us; speedup 1.0000x reference)
//
#include <hip/hip_runtime.h>

#define N_PAIRS 131072
#define NSAMP 10
#define PAIRS_PER_WAVE 4
#define PAD_NUM (-4294967295.0f)

__global__ __launch_bounds__(256, 4) void cmn_kernel(
    const int* __restrict__ users, const int* __restrict__ items,
    const int* __restrict__ sampled, const float* __restrict__ emb_u,
    const float* __restrict__ emb_i, const float* __restrict__ W_w,
    const float* __restrict__ W_b, const float* __restrict__ U_w,
    const float* __restrict__ U_b, const float* __restrict__ bvec,
    const float* __restrict__ vvec, float* __restrict__ out)
{
    // Transposed matrices in LDS, padded stride 65: s*[k*65+d] = *_w[d*64+k]
    // write banks: (lane*65+d)%32 = (lane+d)%32 -> conflict-free
    // read  banks: (k*65+lane)%32 = (k+lane)%32 -> conflict-free
    __shared__ float sU[65 * 64];
    __shared__ float sW[65 * 64];
    const int tid = threadIdx.x;
    #pragma unroll
    for (int i = 0; i < 16; ++i) {
        int e = tid + i * 256;
        int d = e >> 6, k = e & 63;
        sU[k * 65 + d] = U_w[e];
        sW[k * 65 + d] = W_w[e];
    }
    __syncthreads();

    const int lane = tid & 63;
    const int wid = tid >> 6;
    const int gwave = blockIdx.x * 4 + wid;
    const int base_pair = gwave * PAIRS_PER_WAVE;

    const float biasv = U_b[lane] + W_b[lane] + bvec[lane];
    const float vv = vvec[lane];

    float mi[PAIRS_PER_WAVE], o[PAIRS_PER_WAVE], acc[PAIRS_PER_WAVE];

    for (int p = 0; p < PAIRS_PER_WAVE; ++p) {
        const int pair = base_pair + p;
        const int u  = users[pair];
        const int it = items[pair];
        const float Mv = emb_u[u * 64 + lane];
        const float Iv = emb_i[it * 64 + lane];
        const float sv = Mv + Iv;
        mi[p] = Mv * Iv;

        float adjv[NSAMP], dq[NSAMP];
        const int* srow = sampled + u * 10;
        #pragma unroll
        for (int s0 = 0; s0 < NSAMP; ++s0) {
            const int aidx = srow[s0];
            adjv[s0] = emb_u[aidx * 64 + lane];
            dq[s0] = sv * adjv[s0];
        }
        // 10 simultaneous 64-lane butterfly reductions
        #pragma unroll
        for (int off = 32; off > 0; off >>= 1) {
            #pragma unroll
            for (int s0 = 0; s0 < NSAMP; ++s0)
                dq[s0] += __shfl_xor(dq[s0], off, 64);
        }
        // q = 10*dot; where(q != 0, q, PAD); softmax over s
        float m = PAD_NUM;
        #pragma unroll
        for (int s0 = 0; s0 < NSAMP; ++s0) {
            float qv = 10.0f * dq[s0];
            qv = (qv != 0.0f) ? qv : PAD_NUM;
            dq[s0] = qv;
            m = fmaxf(m, qv);
        }
        float esum = 0.0f, ov = 0.0f;
        #pragma unroll
        for (int s0 = 0; s0 < NSAMP; ++s0) {
            const float e = __expf(dq[s0] - m);
            esum += e;
            ov = fmaf(e, adjv[s0], ov);
        }
        o[p] = ov / esum;
        acc[p] = 0.0f;
    }

    // pre[d] = sum_k mi[k]*U_w[d][k] + o[k]*W_w[d][k]  (lane = d)
    #pragma unroll 8
    for (int k = 0; k < 64; ++k) {
        const float uT = sU[k * 65 + lane];
        const float wT = sW[k * 65 + lane];
        #pragma unroll
        for (int p = 0; p < PAIRS_PER_WAVE; ++p) {
            const float mik = __int_as_float(
                __builtin_amdgcn_readlane(__float_as_int(mi[p]), k));
            const float ok = __int_as_float(
                __builtin_amdgcn_readlane(__float_as_int(o[p]), k));
            acc[p] = fmaf(mik, uT, acc[p]);
            acc[p] = fmaf(ok, wT, acc[p]);
        }
    }

    #pragma unroll
    for (int p = 0; p < PAIRS_PER_WAVE; ++p) {
        const float pre = acc[p] + biasv;
        float r = vv * (pre >= 0.0f ? pre : 0.2f * pre);
        #pragma unroll
        for (int off = 32; off > 0; off >>= 1)
            r += __shfl_xor(r, off, 64);
        if (lane == 0) out[base_pair + p] = r;
    }
}

extern "C" void kernel_launch(void* const* d_in, const int* in_sizes, int n_in,
                              void* d_out, int out_size, void* d_ws, size_t ws_size,
                              hipStream_t stream) {
    const int*   users   = (const int*)d_in[0];
    const int*   items   = (const int*)d_in[1];
    const int*   sampled = (const int*)d_in[2];
    const float* emb_u   = (const float*)d_in[3];
    const float* emb_i   = (const float*)d_in[4];
    const float* W_w     = (const float*)d_in[5];
    const float* W_b     = (const float*)d_in[6];
    const float* U_w     = (const float*)d_in[7];
    const float* U_b     = (const float*)d_in[8];
    const float* bvec    = (const float*)d_in[9];
    const float* vvec    = (const float*)d_in[10];
    float* out = (float*)d_out;

    const int blocks = N_PAIRS / (4 * PAIRS_PER_WAVE); // 4 waves/block
    cmn_kernel<<<dim3(blocks), dim3(256), 0, stream>>>(
        users, items, sampled, emb_u, emb_i, W_w, W_b, U_w, U_b, bvec, vvec, out);
}

// Round 2
// 87.072 us; speedup vs baseline: 1.8867x; 1.8867x over previous
//
#include <hip/hip_runtime.h>

#define NSAMP 10
#define PAD_NUM (-4294967295.0f)

typedef __attribute__((ext_vector_type(8))) short short8;
typedef __attribute__((ext_vector_type(4))) float f32x4;

// DPP-fused add: x += dpp_move(x). bound_ctrl=1 -> invalid lanes contribute 0.
template<int CTRL>
__device__ __forceinline__ float dpp_add(float x) {
    int t = __builtin_amdgcn_update_dpp(0, __float_as_int(x), CTRL, 0xF, 0xF, true);
    return x + __int_as_float(t);
}

// sum over each 16-lane row, result replicated in all 16 lanes of the row
__device__ __forceinline__ float row_reduce16(float x) {
    x = dpp_add<0xB1>(x);   // quad_perm(1,0,3,2)  == xor 1
    x = dpp_add<0x4E>(x);   // quad_perm(2,3,0,1)  == xor 2
    x = dpp_add<0x141>(x);  // row_half_mirror     == xor 4 (post-replication)
    x = dpp_add<0x140>(x);  // row_mirror          == xor 8 (post-replication)
    return x;
}

// full 64-lane sum, broadcast to all lanes via readlane(63)
__device__ __forceinline__ float wave_reduce64(float x) {
    x = row_reduce16(x);
    x = dpp_add<0x142>(x);  // row_bcast15
    x = dpp_add<0x143>(x);  // row_bcast31 -> lane 63 has total
    return __int_as_float(__builtin_amdgcn_readlane(__float_as_int(x), 63));
}

__device__ __forceinline__ unsigned short f32_to_bf16_rne(float f) {
    unsigned u = __float_as_uint(f);
    return (unsigned short)((u + 0x7FFFu + ((u >> 16) & 1u)) >> 16);
}

__global__ __launch_bounds__(256, 5) void cmn_kernel(
    const int* __restrict__ users, const int* __restrict__ items,
    const int* __restrict__ sampled, const float* __restrict__ emb_u,
    const float* __restrict__ emb_i, const float* __restrict__ W_w,
    const float* __restrict__ W_b, const float* __restrict__ U_w,
    const float* __restrict__ U_b, const float* __restrict__ bvec,
    const float* __restrict__ vvec, float* __restrict__ out)
{
    // sB: B^T as bf16, sB[d][k], byte = d*256 + 2k, XOR-swizzled ^((d&7)<<4).
    //     B[k][d] = k<64 ? U_w[d][k] : W_w[d][k-64]
    // sA: per-wave A as bf16, sA[p][k] = p<.. row = [mi(0..63) | o(0..63)]
    __shared__ __align__(16) char sB[64 * 256];      // 16 KB
    __shared__ __align__(16) char sA4[4][16 * 256];  // 4 x 4 KB

    const int tid  = threadIdx.x;
    const int lane = tid & 63;
    const int wid  = tid >> 6;
    char* myA = sA4[wid];

    // ---- fill B (block-cooperative, one time; latency hides under gathers) ----
    #pragma unroll
    for (int i = 0; i < 32; ++i) {
        int e = i * 256 + tid;          // e = d*128 + k
        int d = e >> 7, k = e & 127;
        float val = (k < 64) ? U_w[d * 64 + k] : W_w[d * 64 + (k - 64)];
        int byteoff = (d * 256 + 2 * k) ^ ((d & 7) << 4);
        *reinterpret_cast<unsigned short*>(sB + byteoff) = f32_to_bf16_rne(val);
    }

    const int base_pair = (blockIdx.x * 4 + wid) * 16;

    // ---- phase 1: gathers + attention, write A rows (per-wave LDS) ----
    for (int c = 0; c < 4; ++c) {
        #pragma unroll
        for (int p = 0; p < 4; ++p) {
            const int pair = base_pair + c * 4 + p;
            const int u  = users[pair];
            const int it = items[pair];
            const float Mv = emb_u[u * 64 + lane];
            const float Iv = emb_i[it * 64 + lane];
            const float sv = Mv + Iv;
            const float miv = Mv * Iv;
            const int* srow = sampled + u * 10;

            float adjv[NSAMP], q[NSAMP];
            #pragma unroll
            for (int s = 0; s < NSAMP; ++s)
                adjv[s] = emb_u[srow[s] * 64 + lane];
            #pragma unroll
            for (int s = 0; s < NSAMP; ++s)
                q[s] = wave_reduce64(sv * adjv[s]);

            float m = PAD_NUM;
            #pragma unroll
            for (int s = 0; s < NSAMP; ++s) {
                float qv = 10.0f * q[s];
                qv = (qv != 0.0f) ? qv : PAD_NUM;
                q[s] = qv;
                m = fmaxf(m, qv);
            }
            float esum = 0.0f, ov = 0.0f;
            #pragma unroll
            for (int s = 0; s < NSAMP; ++s) {
                const float e = __expf(q[s] - m);
                esum += e;
                ov = fmaf(e, adjv[s], ov);
            }
            ov /= esum;

            // pack (mi, o) -> bf16 pair, store to A row
            unsigned pk;
            asm("v_cvt_pk_bf16_f32 %0, %1, %2" : "=v"(pk) : "v"(miv), "v"(ov));
            const int prow = c * 4 + p;
            const int swz = (prow & 7) << 4;
            *reinterpret_cast<unsigned short*>(myA + ((prow * 256 + 2 * lane) ^ swz)) =
                (unsigned short)pk;
            *reinterpret_cast<unsigned short*>(myA + ((prow * 256 + 128 + 2 * lane) ^ swz)) =
                (unsigned short)(pk >> 16);
        }
    }

    __syncthreads();  // covers sB fill + sA cross-lane visibility

    // ---- phase 2: pre = A[16x128] x B[128x64] via MFMA, fused epilogue ----
    float biasArr[4], vArr[4];
    const int arow = lane & 15;
    const int kg   = lane >> 4;
    #pragma unroll
    for (int t = 0; t < 4; ++t) {
        const int dcol = t * 16 + arow;
        biasArr[t] = U_b[dcol] + W_b[dcol] + bvec[dcol];
        vArr[t]    = vvec[dcol];
    }

    short8 afr[4];
    #pragma unroll
    for (int ks = 0; ks < 4; ++ks) {
        const int off = (arow * 256 + ks * 64 + kg * 16) ^ ((arow & 7) << 4);
        afr[ks] = *reinterpret_cast<const short8*>(myA + off);
    }

    float ps0 = 0.f, ps1 = 0.f, ps2 = 0.f, ps3 = 0.f;
    #pragma unroll
    for (int t = 0; t < 4; ++t) {
        f32x4 acc = {0.f, 0.f, 0.f, 0.f};
        #pragma unroll
        for (int ks = 0; ks < 4; ++ks) {
            const int brow = t * 16 + arow;
            const int off = (brow * 256 + ks * 64 + kg * 16) ^ ((brow & 7) << 4);
            const short8 bfr = *reinterpret_cast<const short8*>(sB + off);
            acc = __builtin_amdgcn_mfma_f32_16x16x32_bf16(afr[ks], bfr, acc, 0, 0, 0);
        }
        #pragma unroll
        for (int r = 0; r < 4; ++r) {
            const float pre = acc[r] + biasArr[t];
            float val = vArr[t] * (pre >= 0.f ? pre : 0.2f * pre);
            val = row_reduce16(val);
            if      (r == 0) ps0 += val;
            else if (r == 1) ps1 += val;
            else if (r == 2) ps2 += val;
            else             ps3 += val;
        }
    }

    const int c4 = lane & 15;
    const float val = (c4 == 0) ? ps0 : (c4 == 1) ? ps1 : (c4 == 2) ? ps2 : ps3;
    if (c4 < 4) out[base_pair + kg * 4 + c4] = val;
}

extern "C" void kernel_launch(void* const* d_in, const int* in_sizes, int n_in,
                              void* d_out, int out_size, void* d_ws, size_t ws_size,
                              hipStream_t stream) {
    const int*   users   = (const int*)d_in[0];
    const int*   items   = (const int*)d_in[1];
    const int*   sampled = (const int*)d_in[2];
    const float* emb_u   = (const float*)d_in[3];
    const float* emb_i   = (const float*)d_in[4];
    const float* W_w     = (const float*)d_in[5];
    const float* W_b     = (const float*)d_in[6];
    const float* U_w     = (const float*)d_in[7];
    const float* U_b     = (const float*)d_in[8];
    const float* bvec    = (const float*)d_in[9];
    const float* vvec    = (const float*)d_in[10];
    float* out = (float*)d_out;

    const int blocks = 131072 / 64;  // 4 waves x 16 pairs per block
    cmn_kernel<<<dim3(blocks), dim3(256), 0, stream>>>(
        users, items, sampled, emb_u, emb_i, W_w, W_b, U_w, U_b, bvec, vvec, out);
}

// Round 3
// 67.164 us; speedup vs baseline: 2.4460x; 1.2964x over previous
//
#include <hip/hip_runtime.h>

#define NSAMP 10
#define PAD_NUM (-4294967295.0f)

typedef __attribute__((ext_vector_type(8))) short short8;
typedef __attribute__((ext_vector_type(4))) float f32x4;
typedef __attribute__((ext_vector_type(4))) int i32x4;

// DPP-fused add: x += dpp_move(x). bound_ctrl=1 -> invalid lanes contribute 0.
template<int CTRL>
__device__ __forceinline__ float dpp_add(float x) {
    int t = __builtin_amdgcn_update_dpp(0, __float_as_int(x), CTRL, 0xF, 0xF, true);
    return x + __int_as_float(t);
}

// sum over each 16-lane row, result replicated in all 16 lanes of the row
__device__ __forceinline__ float row_reduce16(float x) {
    x = dpp_add<0xB1>(x);   // quad_perm(1,0,3,2)  == xor 1
    x = dpp_add<0x4E>(x);   // quad_perm(2,3,0,1)  == xor 2
    x = dpp_add<0x141>(x);  // row_half_mirror     == xor 4
    x = dpp_add<0x140>(x);  // row_mirror          == xor 8
    return x;
}

__device__ __forceinline__ unsigned cvt_pk_bf16(float a, float b) {
    unsigned r;
    asm("v_cvt_pk_bf16_f32 %0, %1, %2" : "=v"(r) : "v"(a), "v"(b));
    return r;  // low = bf16(a), high = bf16(b)
}

__global__ __launch_bounds__(256, 5) void cmn_kernel(
    const int* __restrict__ users, const int* __restrict__ items,
    const int* __restrict__ sampled, const float* __restrict__ emb_u,
    const float* __restrict__ emb_i, const float* __restrict__ W_w,
    const float* __restrict__ W_b, const float* __restrict__ U_w,
    const float* __restrict__ U_b, const float* __restrict__ bvec,
    const float* __restrict__ vvec, float* __restrict__ out)
{
    // sB: bf16, sB[d][k] interleaved k-order: k=2t -> U_w[d][t], k=2t+1 -> W_w[d][t]
    //     byte = d*256 + 2k, XOR-swizzled ^((d&7)<<4)
    // sA: per-wave A rows, same interleaved k-order: [mi0,o0,mi1,o1,...]
    __shared__ __align__(16) char sB[64 * 256];      // 16 KB
    __shared__ __align__(16) char sA4[4][16 * 256];  // 4 x 4 KB

    const int tid  = threadIdx.x;
    const int lane = tid & 63;
    const int wid  = tid >> 6;
    const int j    = lane & 15;   // dim-quad index: owns dims [4j, 4j+4)
    const int g    = lane >> 4;   // pair-slot within wave (4 pairs concurrent)
    char* myA = sA4[wid];

    // ---- fill B (block-cooperative; latency hides under phase-1 gathers) ----
    #pragma unroll
    for (int i2 = 0; i2 < 4; ++i2) {
        const int e  = i2 * 256 + tid;       // 1024 units: (d, t0)
        const int d  = e >> 4;
        const int t0 = (e & 15) * 4;
        const f32x4 u4 = *reinterpret_cast<const f32x4*>(U_w + d * 64 + t0);
        const f32x4 w4 = *reinterpret_cast<const f32x4*>(W_w + d * 64 + t0);
        i32x4 pk;
        pk.x = cvt_pk_bf16(u4.x, w4.x);
        pk.y = cvt_pk_bf16(u4.y, w4.y);
        pk.z = cvt_pk_bf16(u4.z, w4.z);
        pk.w = cvt_pk_bf16(u4.w, w4.w);
        const int byteoff = (d * 256 + 4 * t0) ^ ((d & 7) << 4);
        *reinterpret_cast<i32x4*>(sB + byteoff) = pk;
    }

    const int base_pair = (blockIdx.x * 4 + wid) * 16;

    // ---- phase 1: float4 gathers, per-16-lane-group attention ----
    int u_cur  = users[base_pair + g];
    int it_cur = items[base_pair + g];
    int sidx[NSAMP];
    #pragma unroll
    for (int s = 0; s < NSAMP; ++s) sidx[s] = sampled[u_cur * NSAMP + s];

    #pragma unroll 1
    for (int c = 0; c < 4; ++c) {
        const f32x4 M4 = *reinterpret_cast<const f32x4*>(emb_u + (size_t)u_cur * 64 + 4 * j);
        const f32x4 I4 = *reinterpret_cast<const f32x4*>(emb_i + (size_t)it_cur * 64 + 4 * j);
        f32x4 adj[NSAMP];
        #pragma unroll
        for (int s = 0; s < NSAMP; ++s)
            adj[s] = *reinterpret_cast<const f32x4*>(emb_u + (size_t)sidx[s] * 64 + 4 * j);

        // prefetch next chunk's indices (breaks users->sampled->adj chain)
        int u_nxt = 0, it_nxt = 0;
        int sidx_n[NSAMP] = {0, 0, 0, 0, 0, 0, 0, 0, 0, 0};
        if (c < 3) {
            u_nxt  = users[base_pair + (c + 1) * 4 + g];
            it_nxt = items[base_pair + (c + 1) * 4 + g];
            #pragma unroll
            for (int s = 0; s < NSAMP; ++s) sidx_n[s] = sampled[u_nxt * NSAMP + s];
        }

        const f32x4 sv4 = M4 + I4;
        const f32x4 mi4 = M4 * I4;

        float q[NSAMP];
        #pragma unroll
        for (int s = 0; s < NSAMP; ++s) {
            float d4 = sv4.x * adj[s].x;
            d4 = fmaf(sv4.y, adj[s].y, d4);
            d4 = fmaf(sv4.z, adj[s].z, d4);
            d4 = fmaf(sv4.w, adj[s].w, d4);
            q[s] = row_reduce16(d4);
        }
        float m = PAD_NUM;
        #pragma unroll
        for (int s = 0; s < NSAMP; ++s) {
            float qv = 10.0f * q[s];
            qv = (qv != 0.0f) ? qv : PAD_NUM;
            q[s] = qv;
            m = fmaxf(m, qv);
        }
        float esum = 0.0f;
        f32x4 o4 = {0.f, 0.f, 0.f, 0.f};
        #pragma unroll
        for (int s = 0; s < NSAMP; ++s) {
            const float e = __expf(q[s] - m);
            esum += e;
            o4.x = fmaf(e, adj[s].x, o4.x);
            o4.y = fmaf(e, adj[s].y, o4.y);
            o4.z = fmaf(e, adj[s].z, o4.z);
            o4.w = fmaf(e, adj[s].w, o4.w);
        }
        const float rcp = 1.0f / esum;

        // pack interleaved [mi,o] pairs -> one ds_write_b128 per lane
        i32x4 pk;
        pk.x = cvt_pk_bf16(mi4.x, o4.x * rcp);
        pk.y = cvt_pk_bf16(mi4.y, o4.y * rcp);
        pk.z = cvt_pk_bf16(mi4.z, o4.z * rcp);
        pk.w = cvt_pk_bf16(mi4.w, o4.w * rcp);
        const int prow = c * 4 + g;
        const int off  = (prow * 256 + 16 * j) ^ ((prow & 7) << 4);
        *reinterpret_cast<i32x4*>(myA + off) = pk;

        u_cur = u_nxt;
        it_cur = it_nxt;
        #pragma unroll
        for (int s = 0; s < NSAMP; ++s) sidx[s] = sidx_n[s];
    }

    __syncthreads();  // covers sB fill + sA cross-lane visibility

    // ---- phase 2: pre = A[16x128] x B[128x64] via MFMA, fused epilogue ----
    float biasArr[4], vArr[4];
    const int arow = lane & 15;
    const int kg   = lane >> 4;
    #pragma unroll
    for (int t = 0; t < 4; ++t) {
        const int dcol = t * 16 + arow;
        biasArr[t] = U_b[dcol] + W_b[dcol] + bvec[dcol];
        vArr[t]    = vvec[dcol];
    }

    short8 afr[4];
    #pragma unroll
    for (int ks = 0; ks < 4; ++ks) {
        const int off = (arow * 256 + ks * 64 + kg * 16) ^ ((arow & 7) << 4);
        afr[ks] = *reinterpret_cast<const short8*>(myA + off);
    }

    float ps0 = 0.f, ps1 = 0.f, ps2 = 0.f, ps3 = 0.f;
    #pragma unroll
    for (int t = 0; t < 4; ++t) {
        f32x4 acc = {0.f, 0.f, 0.f, 0.f};
        #pragma unroll
        for (int ks = 0; ks < 4; ++ks) {
            const int brow = t * 16 + arow;
            const int off = (brow * 256 + ks * 64 + kg * 16) ^ ((brow & 7) << 4);
            const short8 bfr = *reinterpret_cast<const short8*>(sB + off);
            acc = __builtin_amdgcn_mfma_f32_16x16x32_bf16(afr[ks], bfr, acc, 0, 0, 0);
        }
        #pragma unroll
        for (int r = 0; r < 4; ++r) {
            const float pre = acc[r] + biasArr[t];
            float val = vArr[t] * (pre >= 0.f ? pre : 0.2f * pre);
            val = row_reduce16(val);
            if      (r == 0) ps0 += val;
            else if (r == 1) ps1 += val;
            else if (r == 2) ps2 += val;
            else             ps3 += val;
        }
    }

    const int c4 = lane & 15;
    const float val = (c4 == 0) ? ps0 : (c4 == 1) ? ps1 : (c4 == 2) ? ps2 : ps3;
    if (c4 < 4) out[base_pair + kg * 4 + c4] = val;
}

extern "C" void kernel_launch(void* const* d_in, const int* in_sizes, int n_in,
                              void* d_out, int out_size, void* d_ws, size_t ws_size,
                              hipStream_t stream) {
    const int*   users   = (const int*)d_in[0];
    const int*   items   = (const int*)d_in[1];
    const int*   sampled = (const int*)d_in[2];
    const float* emb_u   = (const float*)d_in[3];
    const float* emb_i   = (const float*)d_in[4];
    const float* W_w     = (const float*)d_in[5];
    const float* W_b     = (const float*)d_in[6];
    const float* U_w     = (const float*)d_in[7];
    const float* U_b     = (const float*)d_in[8];
    const float* bvec    = (const float*)d_in[9];
    const float* vvec    = (const float*)d_in[10];
    float* out = (float*)d_out;

    const int blocks = 131072 / 64;  // 4 waves x 16 pairs per block
    cmn_kernel<<<dim3(blocks), dim3(256), 0, stream>>>(
        users, items, sampled, emb_u, emb_i, W_w, W_b, U_w, U_b, bvec, vvec, out);
}

// Round 4
// 65.535 us; speedup vs baseline: 2.5068x; 1.0249x over previous
//
#include <hip/hip_runtime.h>

#define NSAMP 10
#define PAD_NUM (-4294967295.0f)

typedef __attribute__((ext_vector_type(8))) short short8;
typedef __attribute__((ext_vector_type(4))) float f32x4;
typedef __attribute__((ext_vector_type(4))) int i32x4;

// DPP-fused add: x += dpp_move(x). bound_ctrl=1 -> invalid lanes contribute 0.
template<int CTRL>
__device__ __forceinline__ float dpp_add(float x) {
    int t = __builtin_amdgcn_update_dpp(0, __float_as_int(x), CTRL, 0xF, 0xF, true);
    return x + __int_as_float(t);
}

// sum over each 16-lane row, result replicated in all 16 lanes of the row
__device__ __forceinline__ float row_reduce16(float x) {
    x = dpp_add<0xB1>(x);   // quad_perm(1,0,3,2)  == xor 1
    x = dpp_add<0x4E>(x);   // quad_perm(2,3,0,1)  == xor 2
    x = dpp_add<0x141>(x);  // row_half_mirror     == xor 4
    x = dpp_add<0x140>(x);  // row_mirror          == xor 8
    return x;
}

__device__ __forceinline__ unsigned cvt_pk_bf16(float a, float b) {
    unsigned r;
    asm("v_cvt_pk_bf16_f32 %0, %1, %2" : "=v"(r) : "v"(a), "v"(b));
    return r;  // low = bf16(a), high = bf16(b)
}

// attention + pack + LDS-write for one chunk of 4 pairs (this lane's group g)
__device__ __forceinline__ void compute_chunk(
    const f32x4 M4, const f32x4 I4, const f32x4* adj,
    char* myA, const int prow, const int j)
{
    const f32x4 sv4 = M4 + I4;
    const f32x4 mi4 = M4 * I4;

    float q[NSAMP];
    #pragma unroll
    for (int s = 0; s < NSAMP; ++s) {
        float d4 = sv4.x * adj[s].x;
        d4 = fmaf(sv4.y, adj[s].y, d4);
        d4 = fmaf(sv4.z, adj[s].z, d4);
        d4 = fmaf(sv4.w, adj[s].w, d4);
        q[s] = row_reduce16(d4);
    }
    float m = PAD_NUM;
    #pragma unroll
    for (int s = 0; s < NSAMP; ++s) {
        float qv = 10.0f * q[s];
        qv = (qv != 0.0f) ? qv : PAD_NUM;
        q[s] = qv;
        m = fmaxf(m, qv);
    }
    float esum = 0.0f;
    f32x4 o4 = {0.f, 0.f, 0.f, 0.f};
    #pragma unroll
    for (int s = 0; s < NSAMP; ++s) {
        const float e = __expf(q[s] - m);
        esum += e;
        o4.x = fmaf(e, adj[s].x, o4.x);
        o4.y = fmaf(e, adj[s].y, o4.y);
        o4.z = fmaf(e, adj[s].z, o4.z);
        o4.w = fmaf(e, adj[s].w, o4.w);
    }
    const float rcp = 1.0f / esum;

    i32x4 pk;
    pk.x = cvt_pk_bf16(mi4.x, o4.x * rcp);
    pk.y = cvt_pk_bf16(mi4.y, o4.y * rcp);
    pk.z = cvt_pk_bf16(mi4.z, o4.z * rcp);
    pk.w = cvt_pk_bf16(mi4.w, o4.w * rcp);
    const int off = (prow * 256 + 16 * j) ^ ((prow & 7) << 4);
    *reinterpret_cast<i32x4*>(myA + off) = pk;
}

#define LOAD_DATA(Mv, Iv, adjv, uu, ii, sx)                                         \
    Mv = *reinterpret_cast<const f32x4*>(emb_u + (size_t)(uu) * 64 + 4 * j);        \
    Iv = *reinterpret_cast<const f32x4*>(emb_i + (size_t)(ii) * 64 + 4 * j);        \
    _Pragma("unroll")                                                                \
    for (int s = 0; s < NSAMP; ++s)                                                  \
        adjv[s] = *reinterpret_cast<const f32x4*>(emb_u + (size_t)(sx)[s] * 64 + 4 * j);

__global__ __launch_bounds__(256, 3) void cmn_kernel(
    const int* __restrict__ users, const int* __restrict__ items,
    const int* __restrict__ sampled, const float* __restrict__ emb_u,
    const float* __restrict__ emb_i, const float* __restrict__ W_w,
    const float* __restrict__ W_b, const float* __restrict__ U_w,
    const float* __restrict__ U_b, const float* __restrict__ bvec,
    const float* __restrict__ vvec, float* __restrict__ out)
{
    __shared__ __align__(16) char sB[64 * 256];      // 16 KB
    __shared__ __align__(16) char sA4[4][16 * 256];  // 4 x 4 KB

    const int tid  = threadIdx.x;
    const int lane = tid & 63;
    const int wid  = tid >> 6;
    const int j    = lane & 15;   // dim-quad index: owns dims [4j, 4j+4)
    const int g    = lane >> 4;   // pair-slot within wave
    char* myA = sA4[wid];

    // ---- fill B (block-cooperative; latency hides under phase-1 gathers) ----
    #pragma unroll
    for (int i2 = 0; i2 < 4; ++i2) {
        const int e  = i2 * 256 + tid;
        const int d  = e >> 4;
        const int t0 = (e & 15) * 4;
        const f32x4 u4 = *reinterpret_cast<const f32x4*>(U_w + d * 64 + t0);
        const f32x4 w4 = *reinterpret_cast<const f32x4*>(W_w + d * 64 + t0);
        i32x4 pk;
        pk.x = cvt_pk_bf16(u4.x, w4.x);
        pk.y = cvt_pk_bf16(u4.y, w4.y);
        pk.z = cvt_pk_bf16(u4.z, w4.z);
        pk.w = cvt_pk_bf16(u4.w, w4.w);
        const int byteoff = (d * 256 + 4 * t0) ^ ((d & 7) << 4);
        *reinterpret_cast<i32x4*>(sB + byteoff) = pk;
    }

    const int base_pair = (blockIdx.x * 4 + wid) * 16;

    // ---- indices for all 4 chunks ----
    const int u0 = users[base_pair + g],      u1 = users[base_pair + 4 + g];
    const int u2 = users[base_pair + 8 + g],  u3 = users[base_pair + 12 + g];
    const int i0 = items[base_pair + g],      i1 = items[base_pair + 4 + g];
    const int i2 = items[base_pair + 8 + g],  i3 = items[base_pair + 12 + g];

    int sx0[NSAMP], sx1[NSAMP];
    #pragma unroll
    for (int s = 0; s < NSAMP; ++s) sx0[s] = sampled[u0 * NSAMP + s];
    #pragma unroll
    for (int s = 0; s < NSAMP; ++s) sx1[s] = sampled[u1 * NSAMP + s];

    // ---- stage 1: issue chunk0 + chunk1 data, prefetch chunk2 sidx ----
    f32x4 MA, IA, adjA[NSAMP], MB, IB, adjB[NSAMP];
    LOAD_DATA(MA, IA, adjA, u0, i0, sx0)
    LOAD_DATA(MB, IB, adjB, u1, i1, sx1)
    #pragma unroll
    for (int s = 0; s < NSAMP; ++s) sx0[s] = sampled[u2 * NSAMP + s];
    __builtin_amdgcn_sched_barrier(0);

    // ---- stage 2: compute chunk0; reload A with chunk2; prefetch chunk3 sidx ----
    compute_chunk(MA, IA, adjA, myA, 0 * 4 + g, j);
    LOAD_DATA(MA, IA, adjA, u2, i2, sx0)
    #pragma unroll
    for (int s = 0; s < NSAMP; ++s) sx1[s] = sampled[u3 * NSAMP + s];
    __builtin_amdgcn_sched_barrier(0);

    // ---- stage 3: compute chunk1; reload B with chunk3 ----
    compute_chunk(MB, IB, adjB, myA, 1 * 4 + g, j);
    LOAD_DATA(MB, IB, adjB, u3, i3, sx1)
    __builtin_amdgcn_sched_barrier(0);

    // ---- stage 4/5: drain ----
    compute_chunk(MA, IA, adjA, myA, 2 * 4 + g, j);
    __builtin_amdgcn_sched_barrier(0);
    compute_chunk(MB, IB, adjB, myA, 3 * 4 + g, j);

    __syncthreads();  // covers sB fill + sA cross-lane visibility

    // ---- phase 2: pre = A[16x128] x B[128x64] via MFMA, fused epilogue ----
    float biasArr[4], vArr[4];
    const int arow = lane & 15;
    const int kg   = lane >> 4;
    #pragma unroll
    for (int t = 0; t < 4; ++t) {
        const int dcol = t * 16 + arow;
        biasArr[t] = U_b[dcol] + W_b[dcol] + bvec[dcol];
        vArr[t]    = vvec[dcol];
    }

    short8 afr[4];
    #pragma unroll
    for (int ks = 0; ks < 4; ++ks) {
        const int off = (arow * 256 + ks * 64 + kg * 16) ^ ((arow & 7) << 4);
        afr[ks] = *reinterpret_cast<const short8*>(myA + off);
    }

    float ps0 = 0.f, ps1 = 0.f, ps2 = 0.f, ps3 = 0.f;
    #pragma unroll
    for (int t = 0; t < 4; ++t) {
        f32x4 acc = {0.f, 0.f, 0.f, 0.f};
        #pragma unroll
        for (int ks = 0; ks < 4; ++ks) {
            const int brow = t * 16 + arow;
            const int off = (brow * 256 + ks * 64 + kg * 16) ^ ((brow & 7) << 4);
            const short8 bfr = *reinterpret_cast<const short8*>(sB + off);
            acc = __builtin_amdgcn_mfma_f32_16x16x32_bf16(afr[ks], bfr, acc, 0, 0, 0);
        }
        #pragma unroll
        for (int r = 0; r < 4; ++r) {
            const float pre = acc[r] + biasArr[t];
            float val = vArr[t] * (pre >= 0.f ? pre : 0.2f * pre);
            val = row_reduce16(val);
            if      (r == 0) ps0 += val;
            else if (r == 1) ps1 += val;
            else if (r == 2) ps2 += val;
            else             ps3 += val;
        }
    }

    const int c4 = lane & 15;
    const float val = (c4 == 0) ? ps0 : (c4 == 1) ? ps1 : (c4 == 2) ? ps2 : ps3;
    if (c4 < 4) out[base_pair + kg * 4 + c4] = val;
}

extern "C" void kernel_launch(void* const* d_in, const int* in_sizes, int n_in,
                              void* d_out, int out_size, void* d_ws, size_t ws_size,
                              hipStream_t stream) {
    const int*   users   = (const int*)d_in[0];
    const int*   items   = (const int*)d_in[1];
    const int*   sampled = (const int*)d_in[2];
    const float* emb_u   = (const float*)d_in[3];
    const float* emb_i   = (const float*)d_in[4];
    const float* W_w     = (const float*)d_in[5];
    const float* W_b     = (const float*)d_in[6];
    const float* U_w     = (const float*)d_in[7];
    const float* U_b     = (const float*)d_in[8];
    const float* bvec    = (const float*)d_in[9];
    const float* vvec    = (const float*)d_in[10];
    float* out = (float*)d_out;

    const int blocks = 131072 / 64;  // 4 waves x 16 pairs per block
    cmn_kernel<<<dim3(blocks), dim3(256), 0, stream>>>(
        users, items, sampled, emb_u, emb_i, W_w, W_b, U_w, U_b, bvec, vvec, out);
}